// Round 7
// baseline (402.299 us; speedup 1.0000x reference)
//
#include <hip/hip_runtime.h>
#include <hip/hip_bf16.h>
#include <stdint.h>

// ---------- types ----------
typedef __attribute__((ext_vector_type(8))) short bf16x8;
typedef __attribute__((ext_vector_type(4))) float f32x4;
typedef __attribute__((ext_vector_type(16))) float f32x16;

#define NB 2
#define NSEQ 2048
#define CDIM 4096
#define NH 32
#define NKV 8
#define HD 128
#define QKV_COLS 6144

static __device__ __forceinline__ unsigned short f2bf(float f) {
    union { float f; unsigned int u; } v; v.f = f;
    unsigned int r = v.u + 0x7fff + ((v.u >> 16) & 1);
    return (unsigned short)(r >> 16);
}
static __device__ __forceinline__ float bf2f(unsigned short b) {
    union { unsigned int u; float f; } v; v.u = ((unsigned int)b) << 16;
    return v.f;
}

static __device__ __forceinline__ void glds16(const void* g, void* l) {
    __builtin_amdgcn_global_load_lds(
        (const __attribute__((address_space(1))) void*)g,
        (__attribute__((address_space(3))) void*)l, 16, 0, 0);
}

static __device__ __forceinline__ unsigned cvtpk(float a, float b) {
    unsigned r; asm("v_cvt_pk_bf16_f32 %0, %1, %2" : "=v"(r) : "v"(a), "v"(b));
    return r;
}

static __device__ __forceinline__ void pack_tile(const f32x16& p, int l, bf16x8& fa, bf16x8& fb) {
    unsigned a0 = cvtpk(p[0], p[1]),   b0 = cvtpk(p[4], p[5]);
    unsigned a1 = cvtpk(p[2], p[3]),   b1 = cvtpk(p[6], p[7]);
    unsigned a2 = cvtpk(p[8], p[9]),   b2 = cvtpk(p[12], p[13]);
    unsigned a3 = cvtpk(p[10], p[11]), b3 = cvtpk(p[14], p[15]);
    union U { unsigned u[4]; bf16x8 v; } ua, ub;
#if __has_builtin(__builtin_amdgcn_permlane32_swap)
    auto r0 = __builtin_amdgcn_permlane32_swap(a0, b0, false, false);
    auto r1 = __builtin_amdgcn_permlane32_swap(a1, b1, false, false);
    auto r2 = __builtin_amdgcn_permlane32_swap(a2, b2, false, false);
    auto r3 = __builtin_amdgcn_permlane32_swap(a3, b3, false, false);
    ua.u[0] = r0[0]; ua.u[1] = r1[0]; ua.u[2] = r0[1]; ua.u[3] = r1[1];
    ub.u[0] = r2[0]; ub.u[1] = r3[0]; ub.u[2] = r2[1]; ub.u[3] = r3[1];
#else
    unsigned a0t = __shfl_xor(a0, 32), b0t = __shfl_xor(b0, 32);
    unsigned a1t = __shfl_xor(a1, 32), b1t = __shfl_xor(b1, 32);
    unsigned a2t = __shfl_xor(a2, 32), b2t = __shfl_xor(b2, 32);
    unsigned a3t = __shfl_xor(a3, 32), b3t = __shfl_xor(b3, 32);
    bool lo = (l < 32);
    ua.u[0] = lo ? a0 : b0t; ua.u[1] = lo ? a1 : b1t; ua.u[2] = lo ? a0t : b0; ua.u[3] = lo ? a1t : b1;
    ub.u[0] = lo ? a2 : b2t; ub.u[1] = lo ? a3 : b3t; ub.u[2] = lo ? a2t : b2; ub.u[3] = lo ? a3t : b3;
#endif
    fa = ua.v; fb = ub.v;
}

// ---------- 1) f32 -> bf16 convert ----------
__global__ void convert_kernel(const float* __restrict__ inA, const float* __restrict__ inW,
                               unsigned short* __restrict__ outA, unsigned short* __restrict__ outW) {
    const long long nA4 = (long long)CDIM * (NB * NSEQ) / 4;
    const long long nW4 = (long long)QKV_COLS * CDIM / 4;
    const long long total = nA4 + nW4;
    for (long long i = blockIdx.x * 256LL + threadIdx.x; i < total; i += (long long)gridDim.x * 256LL) {
        const float4* src; unsigned short* dst; long long j;
        if (i < nA4) { src = (const float4*)inA; dst = outA; j = i; }
        else         { src = (const float4*)inW; dst = outW; j = i - nA4; }
        float4 v = src[j];
        ushort4 o;
        o.x = f2bf(v.x); o.y = f2bf(v.y); o.z = f2bf(v.z); o.w = f2bf(v.w);
        ((ushort4*)dst)[j] = o;
    }
}

// ---------- 2) QKV GEMM: 256x192 tile, BK=64, 8 waves, dbuf + counted vmcnt ----------
// (unchanged from R6: 196us, 1053 TF, MfmaUtil 45.7%, 0 bank conflicts)
#define GPHASE(PP, VNSTR, STAGES) do {                                                        \
    const int r0_ = wm*128 + (PP*2)*16 + lr16;                                                \
    const int r1_ = r0_ + 16;                                                                 \
    bf16x8 a00 = *(const bf16x8*)(lds + cur*32768 + r0_*128 + ((lc4*16) ^ ((r0_&7)<<4)));     \
    bf16x8 a01 = *(const bf16x8*)(lds + cur*32768 + r0_*128 + ((64+lc4*16) ^ ((r0_&7)<<4)));  \
    bf16x8 a10 = *(const bf16x8*)(lds + cur*32768 + r1_*128 + ((lc4*16) ^ ((r1_&7)<<4)));     \
    bf16x8 a11 = *(const bf16x8*)(lds + cur*32768 + r1_*128 + ((64+lc4*16) ^ ((r1_&7)<<4)));  \
    if (PP == 0) {                                                                            \
        _Pragma("unroll")                                                                     \
        for (int nf = 0; nf < 3; ++nf) {                                                      \
            int rb = wn*48 + nf*16 + lr16;                                                    \
            bfr[nf][0] = *(const bf16x8*)(lds + 65536 + cur*24576 + rb*128 + ((lc4*16) ^ ((rb&7)<<4)));    \
            bfr[nf][1] = *(const bf16x8*)(lds + 65536 + cur*24576 + rb*128 + ((64+lc4*16) ^ ((rb&7)<<4))); \
        }                                                                                     \
    }                                                                                         \
    STAGES;                                                                                   \
    __builtin_amdgcn_s_barrier();                                                             \
    asm volatile("s_waitcnt lgkmcnt(0)" ::: "memory");                                        \
    __builtin_amdgcn_s_setprio(1);                                                            \
    _Pragma("unroll")                                                                         \
    for (int nf = 0; nf < 3; ++nf) {                                                          \
        acc[PP*2  ][nf] = __builtin_amdgcn_mfma_f32_16x16x32_bf16(a00, bfr[nf][0], acc[PP*2  ][nf], 0,0,0); \
        acc[PP*2  ][nf] = __builtin_amdgcn_mfma_f32_16x16x32_bf16(a01, bfr[nf][1], acc[PP*2  ][nf], 0,0,0); \
        acc[PP*2+1][nf] = __builtin_amdgcn_mfma_f32_16x16x32_bf16(a10, bfr[nf][0], acc[PP*2+1][nf], 0,0,0); \
        acc[PP*2+1][nf] = __builtin_amdgcn_mfma_f32_16x16x32_bf16(a11, bfr[nf][1], acc[PP*2+1][nf], 0,0,0); \
    }                                                                                         \
    __builtin_amdgcn_s_setprio(0);                                                            \
    asm volatile("s_waitcnt " VNSTR ::: "memory");                                            \
    __builtin_amdgcn_s_barrier();                                                             \
} while (0)

__global__ __launch_bounds__(512) void gemm_qkv8(
    const unsigned short* __restrict__ A, const unsigned short* __restrict__ W,
    unsigned short* __restrict__ qb, unsigned short* __restrict__ kb, unsigned short* __restrict__ vt)
{
    __shared__ unsigned char lds[114688];   // A dbuf @0 (2x32KB), B dbuf @65536 (2x24KB)
    const int bid0 = blockIdx.x;
    const int swz = (bid0 & 7) * 64 + (bid0 >> 3);   // bijective XCD swizzle (512 % 8 == 0)
    const int bm = swz >> 5, bn = swz & 31;          // bn-fast: XCD reads 2 A-panels (4MB, L2-fit) + streams W
    const int tid = threadIdx.x, l = tid & 63, w = tid >> 6;
    const int wm = w >> 2, wn = w & 3;
    const int lr16 = l & 15, lc4 = l >> 4;
    const int tid16 = tid * 16;
    const int abase = (tid >> 8) * 16384 + (tid & 255) * 16;   // wm-interleaved A chunks

    f32x4 acc[8][3] = {};
    bf16x8 bfr[3][2];

    auto stageA = [&](int tb, int kt, int d) {
        int r = d >> 7, c = d & 127;
        int cs = c ^ ((r & 7) << 4);
        glds16(A + (long long)(bm * 256 + r) * CDIM + kt * 64 + (cs >> 1), lds + tb * 32768 + d);
    };
    auto stageB = [&](int tb, int kt, int d) {
        int r = d >> 7, c = d & 127;
        int cs = c ^ ((r & 7) << 4);
        glds16(W + (long long)(bn * 192 + r) * CDIM + kt * 64 + (cs >> 1), lds + 65536 + tb * 24576 + d);
    };

    stageB(0, 0, tid16); stageB(0, 0, tid16 + 8192); stageB(0, 0, tid16 + 16384);
    stageA(0, 0, abase); stageA(0, 0, abase + 4096); stageA(0, 0, abase + 8192); stageA(0, 0, abase + 12288);
    asm volatile("s_waitcnt vmcnt(0)" ::: "memory");
    __builtin_amdgcn_s_barrier();

    for (int t = 0; t < 64; ++t) {
        const int cur = t & 1, tb = cur ^ 1;
        const int tn = (t + 1 < 64) ? t + 1 : 63;
        GPHASE(0, "vmcnt(4)", { stageB(tb, tn, tid16);         stageB(tb, tn, tid16 + 8192); });
        GPHASE(1, "vmcnt(5)", { stageB(tb, tn, tid16 + 16384); stageA(tb, tn, abase);        });
        GPHASE(2, "vmcnt(6)", { stageA(tb, tn, abase + 4096);  stageA(tb, tn, abase + 8192); });
        GPHASE(3, "vmcnt(3)", { stageA(tb, tn, abase + 12288); });
    }

#pragma unroll
    for (int mf = 0; mf < 8; ++mf) {
        int gm0 = bm * 256 + wm * 128 + mf * 16 + lc4 * 4;
        int b = gm0 >> 11, n0 = gm0 & 2047;
#pragma unroll
        for (int nf = 0; nf < 3; ++nf) {
            int coln = bn * 192 + wn * 48 + nf * 16 + lr16;
            if (coln < 4096) {
                unsigned short* dst = qb + (((long long)(b * NH + (coln >> 7)) * NSEQ + n0) << 7) + (coln & 127);
#pragma unroll
                for (int r = 0; r < 4; ++r) dst[(long long)r << 7] = f2bf(acc[mf][nf][r]);
            } else if (coln < 5120) {
                int ck = coln - 4096;
                unsigned short* dst = kb + (((long long)(b * NKV + (ck >> 7)) * NSEQ + n0) << 7) + (ck & 127);
#pragma unroll
                for (int r = 0; r < 4; ++r) dst[(long long)r << 7] = f2bf(acc[mf][nf][r]);
            } else {
                int cv = coln - 5120;
                ushort4 o4;
                o4.x = f2bf(acc[mf][nf][0]); o4.y = f2bf(acc[mf][nf][1]);
                o4.z = f2bf(acc[mf][nf][2]); o4.w = f2bf(acc[mf][nf][3]);
                *(ushort4*)(vt + (((long long)(b * NKV + (cv >> 7)) * HD + (cv & 127)) << 11) + n0) = o4;
            }
        }
    }
}

// ---------- 3) RoPE (folds log2(e)/sqrt(128) into q for exp2-domain softmax) ----------
__global__ void rope_kernel(unsigned short* __restrict__ qb, unsigned short* __restrict__ kb,
                            const float* __restrict__ cosc, const float* __restrict__ sinc,
                            const int* __restrict__ pos) {
    int rowid = blockIdx.x * 4 + (threadIdx.x >> 6);
    int d = threadIdx.x & 63;
    int b = rowid / (40 * NSEQ);
    int rem = rowid % (40 * NSEQ);
    int head = rem / NSEQ, n = rem % NSEQ;
    unsigned short* p;
    float scale;
    if (head < NH) { p = qb + (((long long)(b * NH + head) * NSEQ + n) << 7); scale = 0.12751747934f; }
    else           { p = kb + (((long long)(b * NKV + (head - NH)) * NSEQ + n) << 7); scale = 1.0f; }
    int pid = pos[b * NSEQ + n];
    float c = cosc[pid * HD + d], s = sinc[pid * HD + d];
    float x0 = bf2f(p[d]), x1 = bf2f(p[d + 64]);
    p[d]      = f2bf((x0 * c - x1 * s) * scale);
    p[d + 64] = f2bf((x1 * c + x0 * s) * scale);
}

// ---------- 4) flash attention: 4 waves x 32 q-rows, swapped QK^T, in-reg softmax ----------
// R7 change: K/V LDS DOUBLE-BUFFER (T3 minimum-2-phase): stage(t+1) issued BEFORE compute(t),
// single vmcnt(0)+barrier per iter -> load latency hides under the ~440cyc MFMA+softmax phase.
// Buffer ledger: stage(t+1) writes the buffer last read at iter t-1; its readers retired at the
// end-of-(t-1) barrier, and the stage is issued after that barrier -> race-free.
// Cost: LDS 40->64KB (2 blocks/CU instead of 4); pipeline > TLP per m230 (2ph = 92% of 8ph).
__global__ __launch_bounds__(256) void attn_kernel(
    const unsigned short* __restrict__ qb, const unsigned short* __restrict__ kb,
    const unsigned short* __restrict__ vt, const int* __restrict__ obs,
    float* __restrict__ out)
{
    __shared__ unsigned char k_tile[2][16384];   // [64 kv][128 d] bf16, swizzled
    __shared__ unsigned char v_tile[2][16384];   // [128 d][64 kv] bf16, swizzled

    const int bid = blockIdx.x;
    const int qt = 15 - (bid >> 6);
    const int bh = bid & 63;
    const int b = bh >> 5, h = bh & 31, kvh = h >> 2;
    const int t = threadIdx.x, l = t & 63, w = t >> 6;
    const int lr = l & 31, hi = l >> 5;
    const int swl = (l & 7) << 4;

    const unsigned short* Qb = qb + (((long long)(b * NH + h) * NSEQ + qt * 128 + w * 32) << 7);
    const unsigned short* Kb = kb + (((long long)(b * NKV + kvh) * NSEQ) << 7);
    const unsigned short* Vb = vt + (((long long)(b * NKV + kvh) * HD) << 11);

    bf16x8 qf[8];
#pragma unroll
    for (int dk = 0; dk < 8; ++dk)
        qf[dk] = *(const bf16x8*)(Qb + lr * 128 + dk * 16 + hi * 8);

    f32x16 o[4];
#pragma unroll
    for (int dt = 0; dt < 4; ++dt)
#pragma unroll
        for (int e = 0; e < 16; ++e) o[dt][e] = 0.f;
    float m_run = -1e30f, l_run = 0.f;

    const int qwmax = qt * 128 + w * 32 + 31;
    const int niter = 2 * qt + 2;

    auto stage = [&](int kt, int tb) {
#pragma unroll
        for (int i = 0; i < 4; ++i) {
            int byte = (i * 256 + t) * 16;
            { int r = byte >> 8, c = byte & 255; int cs = c ^ ((r & 7) << 4);
              glds16(Kb + (((long long)(kt * 64 + r)) << 7) + (cs >> 1), k_tile[tb] + byte); }
            { int r = byte >> 7, c = byte & 127; int cs = c ^ ((r & 7) << 4);
              glds16(Vb + (((long long)r) << 11) + kt * 64 + (cs >> 1), v_tile[tb] + byte); }
        }
    };

    // prologue: tile 0 into buffer 0
    stage(0, 0);
    asm volatile("s_waitcnt vmcnt(0)" ::: "memory");
    __syncthreads();

    for (int kt = 0; kt < niter; ++kt) {
        const int cur = kt & 1;
        if (kt + 1 < niter) stage(kt + 1, cur ^ 1);   // prefetch next tile (uniform cond)

        if (kt * 64 <= qwmax) {
            f32x16 s0, s1;
#pragma unroll
            for (int e = 0; e < 16; ++e) { s0[e] = 0.f; s1[e] = 0.f; }
            __builtin_amdgcn_s_setprio(1);
#pragma unroll
            for (int dk = 0; dk < 8; ++dk) {
                int cb = (dk * 32 + hi * 16) ^ swl;
                bf16x8 k0 = *(const bf16x8*)(k_tile[cur] + lr * 256 + cb);
                bf16x8 k1 = *(const bf16x8*)(k_tile[cur] + (32 + lr) * 256 + cb);
                s0 = __builtin_amdgcn_mfma_f32_32x32x16_bf16(k0, qf[dk], s0, 0, 0, 0);
                s1 = __builtin_amdgcn_mfma_f32_32x32x16_bf16(k1, qf[dk], s1, 0, 0, 0);
            }
            __builtin_amdgcn_s_setprio(0);

            if (kt * 64 + 63 > qt * 128 + w * 32) {
                int qg = qt * 128 + w * 32 + lr;
                int base = kt * 64 + hi * 4;
#pragma unroll
                for (int e = 0; e < 16; ++e) {
                    int kv0 = base + (e & 3) + 8 * (e >> 2);
                    if (kv0 > qg)      s0[e] = -1e30f;
                    if (kv0 + 32 > qg) s1[e] = -1e30f;
                }
            }

            float mloc = fmaxf(s0[0], s0[1]);
#pragma unroll
            for (int e = 2; e < 16; ++e) mloc = fmaxf(mloc, s0[e]);
#pragma unroll
            for (int e = 0; e < 16; ++e) mloc = fmaxf(mloc, s1[e]);
            mloc = fmaxf(mloc, __shfl_xor(mloc, 32));

            float mm = m_run;
            if (!__all(mloc - m_run <= 8.f)) {
                mm = fmaxf(m_run, mloc);
                float sc = __builtin_amdgcn_exp2f(m_run - mm);
                l_run *= sc;
#pragma unroll
                for (int dt = 0; dt < 4; ++dt)
#pragma unroll
                    for (int e = 0; e < 16; ++e) o[dt][e] *= sc;
                m_run = mm;
            }
            float sum = 0.f;
#pragma unroll
            for (int e = 0; e < 16; ++e) { s0[e] = __builtin_amdgcn_exp2f(s0[e] - mm); sum += s0[e]; }
#pragma unroll
            for (int e = 0; e < 16; ++e) { s1[e] = __builtin_amdgcn_exp2f(s1[e] - mm); sum += s1[e]; }
            sum += __shfl_xor(sum, 32);
            l_run += sum;

            bf16x8 pb[4];
            pack_tile(s0, l, pb[0], pb[1]);
            pack_tile(s1, l, pb[2], pb[3]);

            __builtin_amdgcn_s_setprio(1);
#pragma unroll
            for (int dt = 0; dt < 4; ++dt) {
#pragma unroll
                for (int kk = 0; kk < 4; ++kk) {
                    int cb = (kk * 32 + hi * 16) ^ swl;
                    bf16x8 vf = *(const bf16x8*)(v_tile[cur] + (dt * 32 + lr) * 128 + cb);
                    o[dt] = __builtin_amdgcn_mfma_f32_32x32x16_bf16(vf, pb[kk], o[dt], 0, 0, 0);
                }
            }
            __builtin_amdgcn_s_setprio(0);
        }

        asm volatile("s_waitcnt vmcnt(0)" ::: "memory");   // next tile's loads complete
        __syncthreads();                                    // all waves done reading cur
    }

    {
        int n = qt * 128 + w * 32 + lr;
        float fac = (1.f / l_run) * ((obs[b * NSEQ + n] == 1) ? 1.f : 0.f);
        unsigned char* slice = k_tile[0] + w * 4096;
        int q2 = l >> 1, half = l & 1;
        long long orow = ((long long)(b * NSEQ + qt * 128 + w * 32 + q2)) << 12;
#pragma unroll
        for (int dt = 0; dt < 4; ++dt) {
#pragma unroll
            for (int e = 0; e < 16; e += 2) {
                int dl = (e & 3) + 8 * (e >> 2) + hi * 4;
                int byte = (lr * 128 + dl * 4) ^ ((lr & 7) << 4);
                *(float2*)(slice + byte) = make_float2(o[dt][e] * fac, o[dt][e + 1] * fac);
            }
#pragma unroll
            for (int j = 0; j < 4; ++j) {
                int byte = (q2 * 128 + half * 64 + j * 16) ^ ((q2 & 7) << 4);
                f32x4 vv = *(const f32x4*)(slice + byte);
                *(f32x4*)(out + orow + h * 128 + dt * 32 + half * 16 + j * 4) = vv;
            }
            __syncthreads();
        }
    }
}

// ---------- launch ----------
extern "C" void kernel_launch(void* const* d_in, const int* in_sizes, int n_in,
                              void* d_out, int out_size, void* d_ws, size_t ws_size,
                              hipStream_t stream) {
    (void)in_sizes; (void)n_in; (void)out_size; (void)ws_size;
    const float* inp  = (const float*)d_in[0];
    const float* wgt  = (const float*)d_in[1];
    const float* cosc = (const float*)d_in[2];
    const float* sinc = (const float*)d_in[3];
    const int* pos = (const int*)d_in[5];
    const int* obs = (const int*)d_in[6];
    float* out = (float*)d_out;

    char* ws = (char*)d_ws;
    unsigned short* A16 = (unsigned short*)(ws);
    unsigned short* W16 = (unsigned short*)(ws + 33554432LL);
    unsigned short* qb  = (unsigned short*)(ws + 83886080LL);
    unsigned short* kb  = (unsigned short*)(ws + 117440512LL);
    unsigned short* vt  = (unsigned short*)(ws + 125829120LL);

    convert_kernel<<<2048, 256, 0, stream>>>(inp, wgt, A16, W16);
    gemm_qkv8<<<512, 512, 0, stream>>>(A16, W16, qb, kb, vt);
    rope_kernel<<<(2 * 40 * NSEQ) / 4, 256, 0, stream>>>(qb, kb, cosc, sinc, pos);
    attn_kernel<<<16 * 64, 256, 0, stream>>>(qb, kb, vt, obs, out);
}

// Round 8
// 348.269 us; speedup vs baseline: 1.1551x; 1.1551x over previous
//
#include <hip/hip_runtime.h>
#include <hip/hip_bf16.h>
#include <stdint.h>

// ---------- types ----------
typedef __attribute__((ext_vector_type(8))) short bf16x8;
typedef __attribute__((ext_vector_type(4))) float f32x4;
typedef __attribute__((ext_vector_type(16))) float f32x16;

#define NB 2
#define NSEQ 2048
#define CDIM 4096
#define NH 32
#define NKV 8
#define HD 128
#define QKV_COLS 6144

static __device__ __forceinline__ unsigned short f2bf(float f) {
    union { float f; unsigned int u; } v; v.f = f;
    unsigned int r = v.u + 0x7fff + ((v.u >> 16) & 1);
    return (unsigned short)(r >> 16);
}
static __device__ __forceinline__ float bf2f(unsigned short b) {
    union { unsigned int u; float f; } v; v.u = ((unsigned int)b) << 16;
    return v.f;
}

static __device__ __forceinline__ void glds16(const void* g, void* l) {
    __builtin_amdgcn_global_load_lds(
        (const __attribute__((address_space(1))) void*)g,
        (__attribute__((address_space(3))) void*)l, 16, 0, 0);
}

static __device__ __forceinline__ unsigned cvtpk(float a, float b) {
    unsigned r; asm("v_cvt_pk_bf16_f32 %0, %1, %2" : "=v"(r) : "v"(a), "v"(b));
    return r;
}

static __device__ __forceinline__ void pack_tile(const f32x16& p, int l, bf16x8& fa, bf16x8& fb) {
    unsigned a0 = cvtpk(p[0], p[1]),   b0 = cvtpk(p[4], p[5]);
    unsigned a1 = cvtpk(p[2], p[3]),   b1 = cvtpk(p[6], p[7]);
    unsigned a2 = cvtpk(p[8], p[9]),   b2 = cvtpk(p[12], p[13]);
    unsigned a3 = cvtpk(p[10], p[11]), b3 = cvtpk(p[14], p[15]);
    union U { unsigned u[4]; bf16x8 v; } ua, ub;
#if __has_builtin(__builtin_amdgcn_permlane32_swap)
    auto r0 = __builtin_amdgcn_permlane32_swap(a0, b0, false, false);
    auto r1 = __builtin_amdgcn_permlane32_swap(a1, b1, false, false);
    auto r2 = __builtin_amdgcn_permlane32_swap(a2, b2, false, false);
    auto r3 = __builtin_amdgcn_permlane32_swap(a3, b3, false, false);
    ua.u[0] = r0[0]; ua.u[1] = r1[0]; ua.u[2] = r0[1]; ua.u[3] = r1[1];
    ub.u[0] = r2[0]; ub.u[1] = r3[0]; ub.u[2] = r2[1]; ub.u[3] = r3[1];
#else
    unsigned a0t = __shfl_xor(a0, 32), b0t = __shfl_xor(b0, 32);
    unsigned a1t = __shfl_xor(a1, 32), b1t = __shfl_xor(b1, 32);
    unsigned a2t = __shfl_xor(a2, 32), b2t = __shfl_xor(b2, 32);
    unsigned a3t = __shfl_xor(a3, 32), b3t = __shfl_xor(b3, 32);
    bool lo = (l < 32);
    ua.u[0] = lo ? a0 : b0t; ua.u[1] = lo ? a1 : b1t; ua.u[2] = lo ? a0t : b0; ua.u[3] = lo ? a1t : b1;
    ub.u[0] = lo ? a2 : b2t; ub.u[1] = lo ? a3 : b3t; ub.u[2] = lo ? a2t : b2; ub.u[3] = lo ? a3t : b3;
#endif
    fa = ua.v; fb = ub.v;
}

// ---------- 1) f32 -> bf16 convert ----------
__global__ void convert_kernel(const float* __restrict__ inA, const float* __restrict__ inW,
                               unsigned short* __restrict__ outA, unsigned short* __restrict__ outW) {
    const long long nA4 = (long long)CDIM * (NB * NSEQ) / 4;
    const long long nW4 = (long long)QKV_COLS * CDIM / 4;
    const long long total = nA4 + nW4;
    for (long long i = blockIdx.x * 256LL + threadIdx.x; i < total; i += (long long)gridDim.x * 256LL) {
        const float4* src; unsigned short* dst; long long j;
        if (i < nA4) { src = (const float4*)inA; dst = outA; j = i; }
        else         { src = (const float4*)inW; dst = outW; j = i - nA4; }
        float4 v = src[j];
        ushort4 o;
        o.x = f2bf(v.x); o.y = f2bf(v.y); o.z = f2bf(v.z); o.w = f2bf(v.w);
        ((ushort4*)dst)[j] = o;
    }
}

// ---------- 2) QKV GEMM: 256x192 tile, BK=64, 8 waves, dbuf + counted vmcnt ----------
// (unchanged from R6: 196us, 1053 TF, MfmaUtil 45.7%, 0 bank conflicts)
#define GPHASE(PP, VNSTR, STAGES) do {                                                        \
    const int r0_ = wm*128 + (PP*2)*16 + lr16;                                                \
    const int r1_ = r0_ + 16;                                                                 \
    bf16x8 a00 = *(const bf16x8*)(lds + cur*32768 + r0_*128 + ((lc4*16) ^ ((r0_&7)<<4)));     \
    bf16x8 a01 = *(const bf16x8*)(lds + cur*32768 + r0_*128 + ((64+lc4*16) ^ ((r0_&7)<<4)));  \
    bf16x8 a10 = *(const bf16x8*)(lds + cur*32768 + r1_*128 + ((lc4*16) ^ ((r1_&7)<<4)));     \
    bf16x8 a11 = *(const bf16x8*)(lds + cur*32768 + r1_*128 + ((64+lc4*16) ^ ((r1_&7)<<4)));  \
    if (PP == 0) {                                                                            \
        _Pragma("unroll")                                                                     \
        for (int nf = 0; nf < 3; ++nf) {                                                      \
            int rb = wn*48 + nf*16 + lr16;                                                    \
            bfr[nf][0] = *(const bf16x8*)(lds + 65536 + cur*24576 + rb*128 + ((lc4*16) ^ ((rb&7)<<4)));    \
            bfr[nf][1] = *(const bf16x8*)(lds + 65536 + cur*24576 + rb*128 + ((64+lc4*16) ^ ((rb&7)<<4))); \
        }                                                                                     \
    }                                                                                         \
    STAGES;                                                                                   \
    __builtin_amdgcn_s_barrier();                                                             \
    asm volatile("s_waitcnt lgkmcnt(0)" ::: "memory");                                        \
    __builtin_amdgcn_s_setprio(1);                                                            \
    _Pragma("unroll")                                                                         \
    for (int nf = 0; nf < 3; ++nf) {                                                          \
        acc[PP*2  ][nf] = __builtin_amdgcn_mfma_f32_16x16x32_bf16(a00, bfr[nf][0], acc[PP*2  ][nf], 0,0,0); \
        acc[PP*2  ][nf] = __builtin_amdgcn_mfma_f32_16x16x32_bf16(a01, bfr[nf][1], acc[PP*2  ][nf], 0,0,0); \
        acc[PP*2+1][nf] = __builtin_amdgcn_mfma_f32_16x16x32_bf16(a10, bfr[nf][0], acc[PP*2+1][nf], 0,0,0); \
        acc[PP*2+1][nf] = __builtin_amdgcn_mfma_f32_16x16x32_bf16(a11, bfr[nf][1], acc[PP*2+1][nf], 0,0,0); \
    }                                                                                         \
    __builtin_amdgcn_s_setprio(0);                                                            \
    asm volatile("s_waitcnt " VNSTR ::: "memory");                                            \
    __builtin_amdgcn_s_barrier();                                                             \
} while (0)

__global__ __launch_bounds__(512) void gemm_qkv8(
    const unsigned short* __restrict__ A, const unsigned short* __restrict__ W,
    unsigned short* __restrict__ qb, unsigned short* __restrict__ kb, unsigned short* __restrict__ vt)
{
    __shared__ unsigned char lds[114688];   // A dbuf @0 (2x32KB), B dbuf @65536 (2x24KB)
    const int bid0 = blockIdx.x;
    const int swz = (bid0 & 7) * 64 + (bid0 >> 3);   // bijective XCD swizzle (512 % 8 == 0)
    const int bm = swz >> 5, bn = swz & 31;          // bn-fast: XCD reads 2 A-panels (4MB, L2-fit) + streams W
    const int tid = threadIdx.x, l = tid & 63, w = tid >> 6;
    const int wm = w >> 2, wn = w & 3;
    const int lr16 = l & 15, lc4 = l >> 4;
    const int tid16 = tid * 16;
    const int abase = (tid >> 8) * 16384 + (tid & 255) * 16;   // wm-interleaved A chunks

    f32x4 acc[8][3] = {};
    bf16x8 bfr[3][2];

    auto stageA = [&](int tb, int kt, int d) {
        int r = d >> 7, c = d & 127;
        int cs = c ^ ((r & 7) << 4);
        glds16(A + (long long)(bm * 256 + r) * CDIM + kt * 64 + (cs >> 1), lds + tb * 32768 + d);
    };
    auto stageB = [&](int tb, int kt, int d) {
        int r = d >> 7, c = d & 127;
        int cs = c ^ ((r & 7) << 4);
        glds16(W + (long long)(bn * 192 + r) * CDIM + kt * 64 + (cs >> 1), lds + 65536 + tb * 24576 + d);
    };

    stageB(0, 0, tid16); stageB(0, 0, tid16 + 8192); stageB(0, 0, tid16 + 16384);
    stageA(0, 0, abase); stageA(0, 0, abase + 4096); stageA(0, 0, abase + 8192); stageA(0, 0, abase + 12288);
    asm volatile("s_waitcnt vmcnt(0)" ::: "memory");
    __builtin_amdgcn_s_barrier();

    for (int t = 0; t < 64; ++t) {
        const int cur = t & 1, tb = cur ^ 1;
        const int tn = (t + 1 < 64) ? t + 1 : 63;
        GPHASE(0, "vmcnt(4)", { stageB(tb, tn, tid16);         stageB(tb, tn, tid16 + 8192); });
        GPHASE(1, "vmcnt(5)", { stageB(tb, tn, tid16 + 16384); stageA(tb, tn, abase);        });
        GPHASE(2, "vmcnt(6)", { stageA(tb, tn, abase + 4096);  stageA(tb, tn, abase + 8192); });
        GPHASE(3, "vmcnt(3)", { stageA(tb, tn, abase + 12288); });
    }

#pragma unroll
    for (int mf = 0; mf < 8; ++mf) {
        int gm0 = bm * 256 + wm * 128 + mf * 16 + lc4 * 4;
        int b = gm0 >> 11, n0 = gm0 & 2047;
#pragma unroll
        for (int nf = 0; nf < 3; ++nf) {
            int coln = bn * 192 + wn * 48 + nf * 16 + lr16;
            if (coln < 4096) {
                unsigned short* dst = qb + (((long long)(b * NH + (coln >> 7)) * NSEQ + n0) << 7) + (coln & 127);
#pragma unroll
                for (int r = 0; r < 4; ++r) dst[(long long)r << 7] = f2bf(acc[mf][nf][r]);
            } else if (coln < 5120) {
                int ck = coln - 4096;
                unsigned short* dst = kb + (((long long)(b * NKV + (ck >> 7)) * NSEQ + n0) << 7) + (ck & 127);
#pragma unroll
                for (int r = 0; r < 4; ++r) dst[(long long)r << 7] = f2bf(acc[mf][nf][r]);
            } else {
                int cv = coln - 5120;
                ushort4 o4;
                o4.x = f2bf(acc[mf][nf][0]); o4.y = f2bf(acc[mf][nf][1]);
                o4.z = f2bf(acc[mf][nf][2]); o4.w = f2bf(acc[mf][nf][3]);
                *(ushort4*)(vt + (((long long)(b * NKV + (cv >> 7)) * HD + (cv & 127)) << 11) + n0) = o4;
            }
        }
    }
}

// ---------- 3) RoPE (folds log2(e)/sqrt(128) into q for exp2-domain softmax) ----------
__global__ void rope_kernel(unsigned short* __restrict__ qb, unsigned short* __restrict__ kb,
                            const float* __restrict__ cosc, const float* __restrict__ sinc,
                            const int* __restrict__ pos) {
    int rowid = blockIdx.x * 4 + (threadIdx.x >> 6);
    int d = threadIdx.x & 63;
    int b = rowid / (40 * NSEQ);
    int rem = rowid % (40 * NSEQ);
    int head = rem / NSEQ, n = rem % NSEQ;
    unsigned short* p;
    float scale;
    if (head < NH) { p = qb + (((long long)(b * NH + head) * NSEQ + n) << 7); scale = 0.12751747934f; }
    else           { p = kb + (((long long)(b * NKV + (head - NH)) * NSEQ + n) << 7); scale = 1.0f; }
    int pid = pos[b * NSEQ + n];
    float c = cosc[pid * HD + d], s = sinc[pid * HD + d];
    float x0 = bf2f(p[d]), x1 = bf2f(p[d + 64]);
    p[d]      = f2bf((x0 * c - x1 * s) * scale);
    p[d + 64] = f2bf((x1 * c + x0 * s) * scale);
}

// ---------- 4) flash attention: 8 waves x 32 q-rows (256 q/block), swapped QK^T ----------
// R8: back to R6's proven single-buffer stage->drain->compute structure (R7 dbuf regressed:
// 2 blocks/CU lost more TLP overlap than the pipeline gained). NEW: 8-wave blocks share each
// staged K/V tile across 2x the compute -> total staged tiles, glds issues, and drain events
// per unit work all halve. Occupancy unchanged (VGPR 128 caps at 16 waves/CU either way).
__global__ __launch_bounds__(512) void attn_kernel(
    const unsigned short* __restrict__ qb, const unsigned short* __restrict__ kb,
    const unsigned short* __restrict__ vt, const int* __restrict__ obs,
    float* __restrict__ out)
{
    __shared__ unsigned char k_tile[16384];   // [64 kv][128 d] bf16, swizzled
    __shared__ unsigned char v_tile[16384];   // [128 d][64 kv] bf16, swizzled

    const int bid = blockIdx.x;
    const int qt = 7 - (bid >> 6);            // descending: longest blocks first (LPT balance)
    const int bh = bid & 63;
    const int b = bh >> 5, h = bh & 31, kvh = h >> 2;
    const int t = threadIdx.x, l = t & 63, w = t >> 6;   // w in 0..7
    const int lr = l & 31, hi = l >> 5;
    const int swl = (l & 7) << 4;

    const unsigned short* Qb = qb + (((long long)(b * NH + h) * NSEQ + qt * 256 + w * 32) << 7);
    const unsigned short* Kb = kb + (((long long)(b * NKV + kvh) * NSEQ) << 7);
    const unsigned short* Vb = vt + (((long long)(b * NKV + kvh) * HD) << 11);

    bf16x8 qf[8];
#pragma unroll
    for (int dk = 0; dk < 8; ++dk)
        qf[dk] = *(const bf16x8*)(Qb + lr * 128 + dk * 16 + hi * 8);

    f32x16 o[4];
#pragma unroll
    for (int dt = 0; dt < 4; ++dt)
#pragma unroll
        for (int e = 0; e < 16; ++e) o[dt][e] = 0.f;
    float m_run = -1e30f, l_run = 0.f;

    const int qwmax = qt * 256 + w * 32 + 31;
    const int niter = 4 * qt + 4;

    for (int kt = 0; kt < niter; ++kt) {
        // stage K,V tile: 512 threads x 2 glds each per buffer half
#pragma unroll
        for (int i = 0; i < 2; ++i) {
            int byte = (i * 512 + t) * 16;
            { int r = byte >> 8, c = byte & 255; int cs = c ^ ((r & 7) << 4);
              glds16(Kb + (((long long)(kt * 64 + r)) << 7) + (cs >> 1), k_tile + byte); }
            { int r = byte >> 7, c = byte & 127; int cs = c ^ ((r & 7) << 4);
              glds16(Vb + (((long long)r) << 11) + kt * 64 + (cs >> 1), v_tile + byte); }
        }
        asm volatile("s_waitcnt vmcnt(0)" ::: "memory");
        __syncthreads();

        if (kt * 64 <= qwmax) {   // wave-level causal skip
            f32x16 s0, s1;
#pragma unroll
            for (int e = 0; e < 16; ++e) { s0[e] = 0.f; s1[e] = 0.f; }
            __builtin_amdgcn_s_setprio(1);
#pragma unroll
            for (int dk = 0; dk < 8; ++dk) {
                int cb = (dk * 32 + hi * 16) ^ swl;
                bf16x8 k0 = *(const bf16x8*)(k_tile + lr * 256 + cb);
                bf16x8 k1 = *(const bf16x8*)(k_tile + (32 + lr) * 256 + cb);
                s0 = __builtin_amdgcn_mfma_f32_32x32x16_bf16(k0, qf[dk], s0, 0, 0, 0);
                s1 = __builtin_amdgcn_mfma_f32_32x32x16_bf16(k1, qf[dk], s1, 0, 0, 0);
            }
            __builtin_amdgcn_s_setprio(0);

            if (kt * 64 + 63 > qt * 256 + w * 32) {   // diagonal-adjacent: apply causal mask
                int qg = qt * 256 + w * 32 + lr;
                int base = kt * 64 + hi * 4;
#pragma unroll
                for (int e = 0; e < 16; ++e) {
                    int kv0 = base + (e & 3) + 8 * (e >> 2);
                    if (kv0 > qg)      s0[e] = -1e30f;
                    if (kv0 + 32 > qg) s1[e] = -1e30f;
                }
            }

            float mloc = fmaxf(s0[0], s0[1]);
#pragma unroll
            for (int e = 2; e < 16; ++e) mloc = fmaxf(mloc, s0[e]);
#pragma unroll
            for (int e = 0; e < 16; ++e) mloc = fmaxf(mloc, s1[e]);
            mloc = fmaxf(mloc, __shfl_xor(mloc, 32));

            float mm = m_run;
            if (!__all(mloc - m_run <= 8.f)) {   // defer-max (T13)
                mm = fmaxf(m_run, mloc);
                float sc = __builtin_amdgcn_exp2f(m_run - mm);
                l_run *= sc;
#pragma unroll
                for (int dt = 0; dt < 4; ++dt)
#pragma unroll
                    for (int e = 0; e < 16; ++e) o[dt][e] *= sc;
                m_run = mm;
            }
            float sum = 0.f;
#pragma unroll
            for (int e = 0; e < 16; ++e) { s0[e] = __builtin_amdgcn_exp2f(s0[e] - mm); sum += s0[e]; }
#pragma unroll
            for (int e = 0; e < 16; ++e) { s1[e] = __builtin_amdgcn_exp2f(s1[e] - mm); sum += s1[e]; }
            sum += __shfl_xor(sum, 32);
            l_run += sum;

            bf16x8 pb[4];
            pack_tile(s0, l, pb[0], pb[1]);
            pack_tile(s1, l, pb[2], pb[3]);

            __builtin_amdgcn_s_setprio(1);
#pragma unroll
            for (int dt = 0; dt < 4; ++dt) {
#pragma unroll
                for (int kk = 0; kk < 4; ++kk) {
                    int cb = (kk * 32 + hi * 16) ^ swl;
                    bf16x8 vf = *(const bf16x8*)(v_tile + (dt * 32 + lr) * 128 + cb);
                    o[dt] = __builtin_amdgcn_mfma_f32_32x32x16_bf16(vf, pb[kk], o[dt], 0, 0, 0);
                }
            }
            __builtin_amdgcn_s_setprio(0);
        }
        __syncthreads();   // all waves done reading before next stage overwrites
    }

    // epilogue: normalize, mask, transpose via per-wave 4KB LDS slice, coalesced f32x4 stores
    {
        int n = qt * 256 + w * 32 + lr;
        float fac = (1.f / l_run) * ((obs[b * NSEQ + n] == 1) ? 1.f : 0.f);
        unsigned char* slice = (w < 4 ? k_tile : v_tile) + (w & 3) * 4096;   // 8 waves x 4KB
        int q2 = l >> 1, half = l & 1;
        long long orow = ((long long)(b * NSEQ + qt * 256 + w * 32 + q2)) << 12;
#pragma unroll
        for (int dt = 0; dt < 4; ++dt) {
#pragma unroll
            for (int e = 0; e < 16; e += 2) {
                int dl = (e & 3) + 8 * (e >> 2) + hi * 4;
                int byte = (lr * 128 + dl * 4) ^ ((lr & 7) << 4);
                *(float2*)(slice + byte) = make_float2(o[dt][e] * fac, o[dt][e + 1] * fac);
            }
#pragma unroll
            for (int j = 0; j < 4; ++j) {
                int byte = (q2 * 128 + half * 64 + j * 16) ^ ((q2 & 7) << 4);
                f32x4 vv = *(const f32x4*)(slice + byte);
                *(f32x4*)(out + orow + h * 128 + dt * 32 + half * 16 + j * 4) = vv;
            }
            __syncthreads();   // slice reuse across dt (cheap; keeps waves' LDS quiescent)
        }
    }
}

// ---------- launch ----------
extern "C" void kernel_launch(void* const* d_in, const int* in_sizes, int n_in,
                              void* d_out, int out_size, void* d_ws, size_t ws_size,
                              hipStream_t stream) {
    (void)in_sizes; (void)n_in; (void)out_size; (void)ws_size;
    const float* inp  = (const float*)d_in[0];
    const float* wgt  = (const float*)d_in[1];
    const float* cosc = (const float*)d_in[2];
    const float* sinc = (const float*)d_in[3];
    const int* pos = (const int*)d_in[5];
    const int* obs = (const int*)d_in[6];
    float* out = (float*)d_out;

    char* ws = (char*)d_ws;
    unsigned short* A16 = (unsigned short*)(ws);
    unsigned short* W16 = (unsigned short*)(ws + 33554432LL);
    unsigned short* qb  = (unsigned short*)(ws + 83886080LL);
    unsigned short* kb  = (unsigned short*)(ws + 117440512LL);
    unsigned short* vt  = (unsigned short*)(ws + 125829120LL);

    convert_kernel<<<2048, 256, 0, stream>>>(inp, wgt, A16, W16);
    gemm_qkv8<<<512, 512, 0, stream>>>(A16, W16, qb, kb, vt);
    rope_kernel<<<(2 * 40 * NSEQ) / 4, 256, 0, stream>>>(qb, kb, cosc, sinc, pos);
    attn_kernel<<<512, 512, 0, stream>>>(qb, kb, vt, obs, out);
}

// Round 9
// 347.715 us; speedup vs baseline: 1.1570x; 1.0016x over previous
//
#include <hip/hip_runtime.h>
#include <hip/hip_bf16.h>
#include <stdint.h>

// ---------- types ----------
typedef __attribute__((ext_vector_type(8))) short bf16x8;
typedef __attribute__((ext_vector_type(4))) float f32x4;
typedef __attribute__((ext_vector_type(16))) float f32x16;

#define NB 2
#define NSEQ 2048
#define CDIM 4096
#define NH 32
#define NKV 8
#define HD 128
#define QKV_COLS 6144

static __device__ __forceinline__ unsigned short f2bf(float f) {
    union { float f; unsigned int u; } v; v.f = f;
    unsigned int r = v.u + 0x7fff + ((v.u >> 16) & 1);
    return (unsigned short)(r >> 16);
}
static __device__ __forceinline__ float bf2f(unsigned short b) {
    union { unsigned int u; float f; } v; v.u = ((unsigned int)b) << 16;
    return v.f;
}

static __device__ __forceinline__ void glds16(const void* g, void* l) {
    __builtin_amdgcn_global_load_lds(
        (const __attribute__((address_space(1))) void*)g,
        (__attribute__((address_space(3))) void*)l, 16, 0, 0);
}

static __device__ __forceinline__ unsigned cvtpk(float a, float b) {
    unsigned r; asm("v_cvt_pk_bf16_f32 %0, %1, %2" : "=v"(r) : "v"(a), "v"(b));
    return r;
}

static __device__ __forceinline__ void pack_tile(const f32x16& p, int l, bf16x8& fa, bf16x8& fb) {
    unsigned a0 = cvtpk(p[0], p[1]),   b0 = cvtpk(p[4], p[5]);
    unsigned a1 = cvtpk(p[2], p[3]),   b1 = cvtpk(p[6], p[7]);
    unsigned a2 = cvtpk(p[8], p[9]),   b2 = cvtpk(p[12], p[13]);
    unsigned a3 = cvtpk(p[10], p[11]), b3 = cvtpk(p[14], p[15]);
    union U { unsigned u[4]; bf16x8 v; } ua, ub;
#if __has_builtin(__builtin_amdgcn_permlane32_swap)
    auto r0 = __builtin_amdgcn_permlane32_swap(a0, b0, false, false);
    auto r1 = __builtin_amdgcn_permlane32_swap(a1, b1, false, false);
    auto r2 = __builtin_amdgcn_permlane32_swap(a2, b2, false, false);
    auto r3 = __builtin_amdgcn_permlane32_swap(a3, b3, false, false);
    ua.u[0] = r0[0]; ua.u[1] = r1[0]; ua.u[2] = r0[1]; ua.u[3] = r1[1];
    ub.u[0] = r2[0]; ub.u[1] = r3[0]; ub.u[2] = r2[1]; ub.u[3] = r3[1];
#else
    unsigned a0t = __shfl_xor(a0, 32), b0t = __shfl_xor(b0, 32);
    unsigned a1t = __shfl_xor(a1, 32), b1t = __shfl_xor(b1, 32);
    unsigned a2t = __shfl_xor(a2, 32), b2t = __shfl_xor(b2, 32);
    unsigned a3t = __shfl_xor(a3, 32), b3t = __shfl_xor(b3, 32);
    bool lo = (l < 32);
    ua.u[0] = lo ? a0 : b0t; ua.u[1] = lo ? a1 : b1t; ua.u[2] = lo ? a0t : b0; ua.u[3] = lo ? a1t : b1;
    ub.u[0] = lo ? a2 : b2t; ub.u[1] = lo ? a3 : b3t; ub.u[2] = lo ? a2t : b2; ub.u[3] = lo ? a3t : b3;
#endif
    fa = ua.v; fb = ub.v;
}

// ---------- 1) f32 -> bf16 convert ----------
__global__ void convert_kernel(const float* __restrict__ inA, const float* __restrict__ inW,
                               unsigned short* __restrict__ outA, unsigned short* __restrict__ outW) {
    const long long nA4 = (long long)CDIM * (NB * NSEQ) / 4;
    const long long nW4 = (long long)QKV_COLS * CDIM / 4;
    const long long total = nA4 + nW4;
    for (long long i = blockIdx.x * 256LL + threadIdx.x; i < total; i += (long long)gridDim.x * 256LL) {
        const float4* src; unsigned short* dst; long long j;
        if (i < nA4) { src = (const float4*)inA; dst = outA; j = i; }
        else         { src = (const float4*)inW; dst = outW; j = i - nA4; }
        float4 v = src[j];
        ushort4 o;
        o.x = f2bf(v.x); o.y = f2bf(v.y); o.z = f2bf(v.z); o.w = f2bf(v.w);
        ((ushort4*)dst)[j] = o;
    }
}

// ---------- 2) QKV GEMM: 256x192 tile, BK=64, 8 waves, dbuf + counted vmcnt ----------
// (unchanged from R6: 196us, 1053 TF, MfmaUtil 46%, 0 bank conflicts)
#define GPHASE(PP, VNSTR, STAGES) do {                                                        \
    const int r0_ = wm*128 + (PP*2)*16 + lr16;                                                \
    const int r1_ = r0_ + 16;                                                                 \
    bf16x8 a00 = *(const bf16x8*)(lds + cur*32768 + r0_*128 + ((lc4*16) ^ ((r0_&7)<<4)));     \
    bf16x8 a01 = *(const bf16x8*)(lds + cur*32768 + r0_*128 + ((64+lc4*16) ^ ((r0_&7)<<4)));  \
    bf16x8 a10 = *(const bf16x8*)(lds + cur*32768 + r1_*128 + ((lc4*16) ^ ((r1_&7)<<4)));     \
    bf16x8 a11 = *(const bf16x8*)(lds + cur*32768 + r1_*128 + ((64+lc4*16) ^ ((r1_&7)<<4)));  \
    if (PP == 0) {                                                                            \
        _Pragma("unroll")                                                                     \
        for (int nf = 0; nf < 3; ++nf) {                                                      \
            int rb = wn*48 + nf*16 + lr16;                                                    \
            bfr[nf][0] = *(const bf16x8*)(lds + 65536 + cur*24576 + rb*128 + ((lc4*16) ^ ((rb&7)<<4)));    \
            bfr[nf][1] = *(const bf16x8*)(lds + 65536 + cur*24576 + rb*128 + ((64+lc4*16) ^ ((rb&7)<<4))); \
        }                                                                                     \
    }                                                                                         \
    STAGES;                                                                                   \
    __builtin_amdgcn_s_barrier();                                                             \
    asm volatile("s_waitcnt lgkmcnt(0)" ::: "memory");                                        \
    __builtin_amdgcn_s_setprio(1);                                                            \
    _Pragma("unroll")                                                                         \
    for (int nf = 0; nf < 3; ++nf) {                                                          \
        acc[PP*2  ][nf] = __builtin_amdgcn_mfma_f32_16x16x32_bf16(a00, bfr[nf][0], acc[PP*2  ][nf], 0,0,0); \
        acc[PP*2  ][nf] = __builtin_amdgcn_mfma_f32_16x16x32_bf16(a01, bfr[nf][1], acc[PP*2  ][nf], 0,0,0); \
        acc[PP*2+1][nf] = __builtin_amdgcn_mfma_f32_16x16x32_bf16(a10, bfr[nf][0], acc[PP*2+1][nf], 0,0,0); \
        acc[PP*2+1][nf] = __builtin_amdgcn_mfma_f32_16x16x32_bf16(a11, bfr[nf][1], acc[PP*2+1][nf], 0,0,0); \
    }                                                                                         \
    __builtin_amdgcn_s_setprio(0);                                                            \
    asm volatile("s_waitcnt " VNSTR ::: "memory");                                            \
    __builtin_amdgcn_s_barrier();                                                             \
} while (0)

__global__ __launch_bounds__(512) void gemm_qkv8(
    const unsigned short* __restrict__ A, const unsigned short* __restrict__ W,
    unsigned short* __restrict__ qb, unsigned short* __restrict__ kb, unsigned short* __restrict__ vt)
{
    __shared__ unsigned char lds[114688];   // A dbuf @0 (2x32KB), B dbuf @65536 (2x24KB)
    const int bid0 = blockIdx.x;
    const int swz = (bid0 & 7) * 64 + (bid0 >> 3);   // bijective XCD swizzle (512 % 8 == 0)
    const int bm = swz >> 5, bn = swz & 31;          // bn-fast: XCD reads 2 A-panels (4MB, L2-fit) + streams W
    const int tid = threadIdx.x, l = tid & 63, w = tid >> 6;
    const int wm = w >> 2, wn = w & 3;
    const int lr16 = l & 15, lc4 = l >> 4;
    const int tid16 = tid * 16;
    const int abase = (tid >> 8) * 16384 + (tid & 255) * 16;   // wm-interleaved A chunks

    f32x4 acc[8][3] = {};
    bf16x8 bfr[3][2];

    auto stageA = [&](int tb, int kt, int d) {
        int r = d >> 7, c = d & 127;
        int cs = c ^ ((r & 7) << 4);
        glds16(A + (long long)(bm * 256 + r) * CDIM + kt * 64 + (cs >> 1), lds + tb * 32768 + d);
    };
    auto stageB = [&](int tb, int kt, int d) {
        int r = d >> 7, c = d & 127;
        int cs = c ^ ((r & 7) << 4);
        glds16(W + (long long)(bn * 192 + r) * CDIM + kt * 64 + (cs >> 1), lds + 65536 + tb * 24576 + d);
    };

    stageB(0, 0, tid16); stageB(0, 0, tid16 + 8192); stageB(0, 0, tid16 + 16384);
    stageA(0, 0, abase); stageA(0, 0, abase + 4096); stageA(0, 0, abase + 8192); stageA(0, 0, abase + 12288);
    asm volatile("s_waitcnt vmcnt(0)" ::: "memory");
    __builtin_amdgcn_s_barrier();

    for (int t = 0; t < 64; ++t) {
        const int cur = t & 1, tb = cur ^ 1;
        const int tn = (t + 1 < 64) ? t + 1 : 63;
        GPHASE(0, "vmcnt(4)", { stageB(tb, tn, tid16);         stageB(tb, tn, tid16 + 8192); });
        GPHASE(1, "vmcnt(5)", { stageB(tb, tn, tid16 + 16384); stageA(tb, tn, abase);        });
        GPHASE(2, "vmcnt(6)", { stageA(tb, tn, abase + 4096);  stageA(tb, tn, abase + 8192); });
        GPHASE(3, "vmcnt(3)", { stageA(tb, tn, abase + 12288); });
    }

#pragma unroll
    for (int mf = 0; mf < 8; ++mf) {
        int gm0 = bm * 256 + wm * 128 + mf * 16 + lc4 * 4;
        int b = gm0 >> 11, n0 = gm0 & 2047;
#pragma unroll
        for (int nf = 0; nf < 3; ++nf) {
            int coln = bn * 192 + wn * 48 + nf * 16 + lr16;
            if (coln < 4096) {
                unsigned short* dst = qb + (((long long)(b * NH + (coln >> 7)) * NSEQ + n0) << 7) + (coln & 127);
#pragma unroll
                for (int r = 0; r < 4; ++r) dst[(long long)r << 7] = f2bf(acc[mf][nf][r]);
            } else if (coln < 5120) {
                int ck = coln - 4096;
                unsigned short* dst = kb + (((long long)(b * NKV + (ck >> 7)) * NSEQ + n0) << 7) + (ck & 127);
#pragma unroll
                for (int r = 0; r < 4; ++r) dst[(long long)r << 7] = f2bf(acc[mf][nf][r]);
            } else {
                int cv = coln - 5120;
                ushort4 o4;
                o4.x = f2bf(acc[mf][nf][0]); o4.y = f2bf(acc[mf][nf][1]);
                o4.z = f2bf(acc[mf][nf][2]); o4.w = f2bf(acc[mf][nf][3]);
                *(ushort4*)(vt + (((long long)(b * NKV + (cv >> 7)) * HD + (cv & 127)) << 11) + n0) = o4;
            }
        }
    }
}

// ---------- 3) RoPE (folds log2(e)/sqrt(128) into q for exp2-domain softmax) ----------
__global__ void rope_kernel(unsigned short* __restrict__ qb, unsigned short* __restrict__ kb,
                            const float* __restrict__ cosc, const float* __restrict__ sinc,
                            const int* __restrict__ pos) {
    int rowid = blockIdx.x * 4 + (threadIdx.x >> 6);
    int d = threadIdx.x & 63;
    int b = rowid / (40 * NSEQ);
    int rem = rowid % (40 * NSEQ);
    int head = rem / NSEQ, n = rem % NSEQ;
    unsigned short* p;
    float scale;
    if (head < NH) { p = qb + (((long long)(b * NH + head) * NSEQ + n) << 7); scale = 0.12751747934f; }
    else           { p = kb + (((long long)(b * NKV + (head - NH)) * NSEQ + n) << 7); scale = 1.0f; }
    int pid = pos[b * NSEQ + n];
    float c = cosc[pid * HD + d], s = sinc[pid * HD + d];
    float x0 = bf2f(p[d]), x1 = bf2f(p[d + 64]);
    p[d]      = f2bf((x0 * c - x1 * s) * scale);
    p[d + 64] = f2bf((x1 * c + x0 * s) * scale);
}

// ---------- 4) flash attention: 8 waves x 32 q-rows, swapped QK^T, K/V double-buffer ----------
// R9: dbuf is now OCCUPANCY-FREE: VGPR=128 caps residency at 16 waves/CU = 2 blocks/CU whether
// LDS is 32KB or 64KB (R7's dbuf failed only because 4-wave blocks dropped 4->2 blocks/CU).
// stage(t+1) issues at iter start into the buffer whose readers retired at end-of-(t-1) barrier;
// compute(t) runs over the loads; single vmcnt(0)+barrier at iter end.
__global__ __launch_bounds__(512) void attn_kernel(
    const unsigned short* __restrict__ qb, const unsigned short* __restrict__ kb,
    const unsigned short* __restrict__ vt, const int* __restrict__ obs,
    float* __restrict__ out)
{
    __shared__ unsigned char k_tile[2][16384];   // [64 kv][128 d] bf16, swizzled
    __shared__ unsigned char v_tile[2][16384];   // [128 d][64 kv] bf16, swizzled

    const int bid = blockIdx.x;
    const int qt = 7 - (bid >> 6);            // descending: longest blocks first (LPT balance)
    const int bh = bid & 63;
    const int b = bh >> 5, h = bh & 31, kvh = h >> 2;
    const int t = threadIdx.x, l = t & 63, w = t >> 6;   // w in 0..7
    const int lr = l & 31, hi = l >> 5;
    const int swl = (l & 7) << 4;

    const unsigned short* Qb = qb + (((long long)(b * NH + h) * NSEQ + qt * 256 + w * 32) << 7);
    const unsigned short* Kb = kb + (((long long)(b * NKV + kvh) * NSEQ) << 7);
    const unsigned short* Vb = vt + (((long long)(b * NKV + kvh) * HD) << 11);

    bf16x8 qf[8];
#pragma unroll
    for (int dk = 0; dk < 8; ++dk)
        qf[dk] = *(const bf16x8*)(Qb + lr * 128 + dk * 16 + hi * 8);

    f32x16 o[4];
#pragma unroll
    for (int dt = 0; dt < 4; ++dt)
#pragma unroll
        for (int e = 0; e < 16; ++e) o[dt][e] = 0.f;
    float m_run = -1e30f, l_run = 0.f;

    const int qwmax = qt * 256 + w * 32 + 31;
    const int niter = 4 * qt + 4;

    auto stage = [&](int kt, int tb) {
#pragma unroll
        for (int i = 0; i < 2; ++i) {
            int byte = (i * 512 + t) * 16;
            { int r = byte >> 8, c = byte & 255; int cs = c ^ ((r & 7) << 4);
              glds16(Kb + (((long long)(kt * 64 + r)) << 7) + (cs >> 1), k_tile[tb] + byte); }
            { int r = byte >> 7, c = byte & 127; int cs = c ^ ((r & 7) << 4);
              glds16(Vb + (((long long)r) << 11) + kt * 64 + (cs >> 1), v_tile[tb] + byte); }
        }
    };

    // prologue: tile 0 into buffer 0
    stage(0, 0);
    asm volatile("s_waitcnt vmcnt(0)" ::: "memory");
    __syncthreads();

    for (int kt = 0; kt < niter; ++kt) {
        const int cur = kt & 1;
        if (kt + 1 < niter) stage(kt + 1, cur ^ 1);   // prefetch next tile (uniform cond)

        if (kt * 64 <= qwmax) {   // wave-level causal skip
            f32x16 s0, s1;
#pragma unroll
            for (int e = 0; e < 16; ++e) { s0[e] = 0.f; s1[e] = 0.f; }
            __builtin_amdgcn_s_setprio(1);
#pragma unroll
            for (int dk = 0; dk < 8; ++dk) {
                int cb = (dk * 32 + hi * 16) ^ swl;
                bf16x8 k0 = *(const bf16x8*)(k_tile[cur] + lr * 256 + cb);
                bf16x8 k1 = *(const bf16x8*)(k_tile[cur] + (32 + lr) * 256 + cb);
                s0 = __builtin_amdgcn_mfma_f32_32x32x16_bf16(k0, qf[dk], s0, 0, 0, 0);
                s1 = __builtin_amdgcn_mfma_f32_32x32x16_bf16(k1, qf[dk], s1, 0, 0, 0);
            }
            __builtin_amdgcn_s_setprio(0);

            if (kt * 64 + 63 > qt * 256 + w * 32) {   // diagonal-adjacent: causal mask
                int qg = qt * 256 + w * 32 + lr;
                int base = kt * 64 + hi * 4;
#pragma unroll
                for (int e = 0; e < 16; ++e) {
                    int kv0 = base + (e & 3) + 8 * (e >> 2);
                    if (kv0 > qg)      s0[e] = -1e30f;
                    if (kv0 + 32 > qg) s1[e] = -1e30f;
                }
            }

            float mloc = fmaxf(s0[0], s0[1]);
#pragma unroll
            for (int e = 2; e < 16; ++e) mloc = fmaxf(mloc, s0[e]);
#pragma unroll
            for (int e = 0; e < 16; ++e) mloc = fmaxf(mloc, s1[e]);
            mloc = fmaxf(mloc, __shfl_xor(mloc, 32));

            float mm = m_run;
            if (!__all(mloc - m_run <= 8.f)) {   // defer-max (T13)
                mm = fmaxf(m_run, mloc);
                float sc = __builtin_amdgcn_exp2f(m_run - mm);
                l_run *= sc;
#pragma unroll
                for (int dt = 0; dt < 4; ++dt)
#pragma unroll
                    for (int e = 0; e < 16; ++e) o[dt][e] *= sc;
                m_run = mm;
            }
            float sum = 0.f;
#pragma unroll
            for (int e = 0; e < 16; ++e) { s0[e] = __builtin_amdgcn_exp2f(s0[e] - mm); sum += s0[e]; }
#pragma unroll
            for (int e = 0; e < 16; ++e) { s1[e] = __builtin_amdgcn_exp2f(s1[e] - mm); sum += s1[e]; }
            sum += __shfl_xor(sum, 32);
            l_run += sum;

            bf16x8 pb[4];
            pack_tile(s0, l, pb[0], pb[1]);
            pack_tile(s1, l, pb[2], pb[3]);

            __builtin_amdgcn_s_setprio(1);
#pragma unroll
            for (int dt = 0; dt < 4; ++dt) {
#pragma unroll
                for (int kk = 0; kk < 4; ++kk) {
                    int cb = (kk * 32 + hi * 16) ^ swl;
                    bf16x8 vf = *(const bf16x8*)(v_tile[cur] + (dt * 32 + lr) * 128 + cb);
                    o[dt] = __builtin_amdgcn_mfma_f32_32x32x16_bf16(vf, pb[kk], o[dt], 0, 0, 0);
                }
            }
            __builtin_amdgcn_s_setprio(0);
        }

        asm volatile("s_waitcnt vmcnt(0)" ::: "memory");   // prefetched tile landed
        __syncthreads();                                    // all waves done reading cur
    }

    // epilogue: normalize, mask, transpose via per-wave 4KB LDS slice, coalesced f32x4 stores
    {
        int n = qt * 256 + w * 32 + lr;
        float fac = (1.f / l_run) * ((obs[b * NSEQ + n] == 1) ? 1.f : 0.f);
        unsigned char* slice = &k_tile[0][0] + w * 4096;   // 8 waves x 4KB within the 32KB k_tile
        int q2 = l >> 1, half = l & 1;
        long long orow = ((long long)(b * NSEQ + qt * 256 + w * 32 + q2)) << 12;
#pragma unroll
        for (int dt = 0; dt < 4; ++dt) {
#pragma unroll
            for (int e = 0; e < 16; e += 2) {
                int dl = (e & 3) + 8 * (e >> 2) + hi * 4;
                int byte = (lr * 128 + dl * 4) ^ ((lr & 7) << 4);
                *(float2*)(slice + byte) = make_float2(o[dt][e] * fac, o[dt][e + 1] * fac);
            }
#pragma unroll
            for (int j = 0; j < 4; ++j) {
                int byte = (q2 * 128 + half * 64 + j * 16) ^ ((q2 & 7) << 4);
                f32x4 vv = *(const f32x4*)(slice + byte);
                *(f32x4*)(out + orow + h * 128 + dt * 32 + half * 16 + j * 4) = vv;
            }
            __syncthreads();
        }
    }
}

// ---------- launch ----------
extern "C" void kernel_launch(void* const* d_in, const int* in_sizes, int n_in,
                              void* d_out, int out_size, void* d_ws, size_t ws_size,
                              hipStream_t stream) {
    (void)in_sizes; (void)n_in; (void)out_size; (void)ws_size;
    const float* inp  = (const float*)d_in[0];
    const float* wgt  = (const float*)d_in[1];
    const float* cosc = (const float*)d_in[2];
    const float* sinc = (const float*)d_in[3];
    const int* pos = (const int*)d_in[5];
    const int* obs = (const int*)d_in[6];
    float* out = (float*)d_out;

    char* ws = (char*)d_ws;
    unsigned short* A16 = (unsigned short*)(ws);
    unsigned short* W16 = (unsigned short*)(ws + 33554432LL);
    unsigned short* qb  = (unsigned short*)(ws + 83886080LL);
    unsigned short* kb  = (unsigned short*)(ws + 117440512LL);
    unsigned short* vt  = (unsigned short*)(ws + 125829120LL);

    convert_kernel<<<2048, 256, 0, stream>>>(inp, wgt, A16, W16);
    gemm_qkv8<<<512, 512, 0, stream>>>(A16, W16, qb, kb, vt);
    rope_kernel<<<(2 * 40 * NSEQ) / 4, 256, 0, stream>>>(qb, kb, cosc, sinc, pos);
    attn_kernel<<<512, 512, 0, stream>>>(qb, kb, vt, obs, out);
}